// Round 10
// baseline (257.596 us; speedup 1.0000x reference)
//
#include <hip/hip_runtime.h>
#include <hip/hip_bf16.h>

#define B_  2
#define T_  4096
#define C_  768
#define H_  12
#define D_  64
#define BT_ (B_*T_)   // 8192

typedef __attribute__((ext_vector_type(8))) short short8;
typedef __attribute__((ext_vector_type(4))) short short4b;
typedef __attribute__((ext_vector_type(4))) float f32x4;

union U32x2 { unsigned u[2]; short4b s4; };

__device__ __forceinline__ ushort f2bf(float f) {
  union { __hip_bfloat16 b; ushort u; } cv; cv.b = __float2bfloat16(f); return cv.u;
}
__device__ __forceinline__ float bf2f(ushort u) {
  unsigned x = ((unsigned)u) << 16; float f; __builtin_memcpy(&f, &x, 4); return f;
}
__device__ __forceinline__ unsigned pack2(float a, float b) {
  return (unsigned)f2bf(a) | ((unsigned)f2bf(b) << 16);
}

__device__ __forceinline__ f32x4 mfma32(short8 a, short8 b, f32x4 c) {
  return __builtin_amdgcn_mfma_f32_16x16x32_bf16(a, b, c, 0, 0, 0);
}
// 16x16x16 bf16 MFMA (K=16, A/B k-granule = lg*4+i)
__device__ __forceinline__ f32x4 mfma16(short4b a, short4b b, f32x4 c) {
#if __has_builtin(__builtin_amdgcn_mfma_f32_16x16x16bf16_1k)
  return __builtin_amdgcn_mfma_f32_16x16x16bf16_1k(a, b, c, 0, 0, 0);
#elif __has_builtin(__builtin_amdgcn_mfma_f32_16x16x16_bf16)
  return __builtin_amdgcn_mfma_f32_16x16x16_bf16(a, b, c, 0, 0, 0);
#else
  asm("v_mfma_f32_16x16x16_bf16 %0, %1, %2, %0" : "+v"(c) : "v"(a), "v"(b));
  return c;
#endif
}

// ---------------- elementwise converts ----------------
__global__ void k_f32_to_bf16(const float* __restrict__ in, ushort* __restrict__ out, int n4) {
  int i = blockIdx.x * blockDim.x + threadIdx.x;
  if (i >= n4) return;
  const float4 v = ((const float4*)in)[i];
  ushort4 o;
  o.x = f2bf(v.x); o.y = f2bf(v.y); o.z = f2bf(v.z); o.w = f2bf(v.w);
  ((ushort4*)out)[i] = o;
}

__global__ void k_w_to_bf16(const float* __restrict__ w0, const float* __restrict__ w1,
                            const float* __restrict__ w2, const float* __restrict__ w3,
                            ushort* __restrict__ o0, ushort* __restrict__ o1,
                            ushort* __restrict__ o2, ushort* __restrict__ o3, int n4) {
  int i = blockIdx.x * blockDim.x + threadIdx.x;
  if (i >= n4) return;
  const int sel = blockIdx.y;
  const float* in = sel == 0 ? w0 : (sel == 1 ? w1 : (sel == 2 ? w2 : w3));
  ushort* out = sel == 0 ? o0 : (sel == 1 ? o1 : (sel == 2 ? o2 : o3));
  const float4 v = ((const float4*)in)[i];
  ushort4 o;
  o.x = f2bf(v.x); o.y = f2bf(v.y); o.z = f2bf(v.z); o.w = f2bf(v.w);
  ((ushort4*)out)[i] = o;
}

// rope tables + zero the attn task counter (runs before k_attn every launch)
__global__ void k_rope_tab(float* __restrict__ ctab, float* __restrict__ stab,
                           unsigned* __restrict__ ctr) {
  int i = blockIdx.x * blockDim.x + threadIdx.x;  // T_*32 threads
  if (i == 0) *ctr = 0u;
  int t = i >> 5, p = i & 31;
  float inv = 1.0f / powf(10000.0f, (2.0f * (float)p) / 64.0f);
  float a = (float)t * inv;
  ctab[i] = cosf(a); stab[i] = sinf(a);
}

// fused in-place RoPE on q and k (blockIdx.y: 0=q, 1=k); q gets log2(e)/8 folded
__global__ void k_rope_qk(ushort* __restrict__ qx, ushort* __restrict__ kx,
                          const float* __restrict__ ctab, const float* __restrict__ stab) {
  int i = blockIdx.x * blockDim.x + threadIdx.x;  // B_*H_*T_*32 threads
  ushort* x = blockIdx.y ? kx : qx;
  const float scale = blockIdx.y ? 1.0f : 0.125f * 1.4426950408889634f;
  int p = i & 31, t = (i >> 5) & (T_ - 1);
  size_t base = ((size_t)(i >> 5)) * 64 + (size_t)p * 2;
  uint xv = *(const uint*)(x + base);
  float x1 = bf2f((ushort)(xv & 0xffffu)), x2 = bf2f((ushort)(xv >> 16));
  float c = ctab[t * 32 + p], s = stab[t * 32 + p];
  float o1 = (x1 * c - x2 * s) * scale, o2 = (x1 * s + x2 * c) * scale;
  *(uint*)(x + base) = (uint)f2bf(o1) | ((uint)f2bf(o2) << 16);
}

// ---------------- QKV projection GEMM ----------------
__global__ __launch_bounds__(256) void k_qkv_gemm(
    const ushort* __restrict__ xb, const ushort* __restrict__ wq,
    const ushort* __restrict__ wk, const ushort* __restrict__ wv,
    const float* __restrict__ bq, const float* __restrict__ bk, const float* __restrict__ bv,
    ushort* __restrict__ qo, ushort* __restrict__ ko, ushort* __restrict__ vo) {
  __shared__ __align__(16) ushort As[128 * 72];
  __shared__ __align__(16) ushort Bs[128 * 72];
  const int tid = threadIdx.x, l = tid & 63, w = tid >> 6;
  const int lr = l & 15, lg = l >> 4;
  const int m0 = blockIdx.x * 128;
  const int n0g = blockIdx.y * 128;
  const int proj = n0g / 768;
  const int n0 = n0g % 768;
  const ushort* wsrc = proj == 0 ? wq : (proj == 1 ? wk : wv);
  const int wr = (w >> 1) * 64, wc = (w & 1) * 64;

  f32x4 acc[4][4];
  #pragma unroll
  for (int a = 0; a < 4; ++a)
    #pragma unroll
    for (int b = 0; b < 4; ++b) acc[a][b] = (f32x4){0.f, 0.f, 0.f, 0.f};

  for (int k0 = 0; k0 < 768; k0 += 64) {
    #pragma unroll
    for (int i = 0; i < 4; ++i) {
      int seg = tid + i * 256;
      int row = seg >> 3, c8 = (seg & 7) << 3;
      *(short8*)&As[row * 72 + c8] = *(const short8*)(xb + (size_t)(m0 + row) * 768 + k0 + c8);
      *(short8*)&Bs[row * 72 + c8] = *(const short8*)(wsrc + (size_t)(n0 + row) * 768 + k0 + c8);
    }
    __syncthreads();
    #pragma unroll
    for (int kk = 0; kk < 2; ++kk) {
      short8 af[4], bf[4];
      #pragma unroll
      for (int mi = 0; mi < 4; ++mi)
        af[mi] = *(const short8*)&As[(wr + mi * 16 + lr) * 72 + kk * 32 + lg * 8];
      #pragma unroll
      for (int ni = 0; ni < 4; ++ni)
        bf[ni] = *(const short8*)&Bs[(wc + ni * 16 + lr) * 72 + kk * 32 + lg * 8];
      #pragma unroll
      for (int mi = 0; mi < 4; ++mi)
        #pragma unroll
        for (int ni = 0; ni < 4; ++ni)
          acc[mi][ni] = mfma32(af[mi], bf[ni], acc[mi][ni]);
    }
    __syncthreads();
  }

  const float* bias = proj == 0 ? bq : (proj == 1 ? bk : bv);
  if (proj == 2) {
    #pragma unroll
    for (int mi = 0; mi < 4; ++mi) {
      #pragma unroll
      for (int ni = 0; ni < 4; ++ni) {
        int colc = n0 + wc + ni * 16 + lr;
        float bb = bias[colc];
        int h = colc >> 6, d = colc & 63;
        int row0 = m0 + wr + mi * 16 + lg * 4;
        int b = row0 >> 12, t0 = row0 & (T_ - 1);
        ushort4 pk;
        pk.x = f2bf(acc[mi][ni][0] + bb);
        pk.y = f2bf(acc[mi][ni][1] + bb);
        pk.z = f2bf(acc[mi][ni][2] + bb);
        pk.w = f2bf(acc[mi][ni][3] + bb);
        *(ushort4*)(vo + (((size_t)b * H_ + h) * 64 + d) * T_ + t0) = pk;
      }
    }
  } else {
    ushort* dst = proj == 0 ? qo : ko;
    #pragma unroll
    for (int mi = 0; mi < 4; ++mi) {
      #pragma unroll
      for (int ni = 0; ni < 4; ++ni) {
        int colc = n0 + wc + ni * 16 + lr;
        float bb = bias[colc];
        int h = colc >> 6, d = colc & 63;
        #pragma unroll
        for (int j = 0; j < 4; ++j) {
          int row = m0 + wr + mi * 16 + lg * 4 + j;
          int b = row >> 12, t = row & (T_ - 1);
          dst[((((size_t)b * H_ + h) << 12) + t) * 64 + d] = f2bf(acc[mi][ni][j] + bb);
        }
      }
    }
  }
}

// ---------------- output projection GEMM (f32 out) ----------------
__global__ __launch_bounds__(256) void k_proj_gemm(
    const ushort* __restrict__ yb, const ushort* __restrict__ wp,
    const float* __restrict__ bp, float* __restrict__ out) {
  __shared__ __align__(16) ushort As[128 * 72];
  __shared__ __align__(16) ushort Bs[128 * 72];
  const int tid = threadIdx.x, l = tid & 63, w = tid >> 6;
  const int lr = l & 15, lg = l >> 4;
  const int m0 = blockIdx.x * 128;
  const int n0 = blockIdx.y * 128;
  const int wr = (w >> 1) * 64, wc = (w & 1) * 64;

  f32x4 acc[4][4];
  #pragma unroll
  for (int a = 0; a < 4; ++a)
    #pragma unroll
    for (int b = 0; b < 4; ++b) acc[a][b] = (f32x4){0.f, 0.f, 0.f, 0.f};

  for (int k0 = 0; k0 < 768; k0 += 64) {
    #pragma unroll
    for (int i = 0; i < 4; ++i) {
      int seg = tid + i * 256;
      int row = seg >> 3, c8 = (seg & 7) << 3;
      *(short8*)&As[row * 72 + c8] = *(const short8*)(yb + (size_t)(m0 + row) * 768 + k0 + c8);
      *(short8*)&Bs[row * 72 + c8] = *(const short8*)(wp + (size_t)(n0 + row) * 768 + k0 + c8);
    }
    __syncthreads();
    #pragma unroll
    for (int kk = 0; kk < 2; ++kk) {
      short8 af[4], bf[4];
      #pragma unroll
      for (int mi = 0; mi < 4; ++mi)
        af[mi] = *(const short8*)&As[(wr + mi * 16 + lr) * 72 + kk * 32 + lg * 8];
      #pragma unroll
      for (int ni = 0; ni < 4; ++ni)
        bf[ni] = *(const short8*)&Bs[(wc + ni * 16 + lr) * 72 + kk * 32 + lg * 8];
      #pragma unroll
      for (int mi = 0; mi < 4; ++mi)
        #pragma unroll
        for (int ni = 0; ni < 4; ++ni)
          acc[mi][ni] = mfma32(af[mi], bf[ni], acc[mi][ni]);
    }
    __syncthreads();
  }

  #pragma unroll
  for (int mi = 0; mi < 4; ++mi)
    #pragma unroll
    for (int ni = 0; ni < 4; ++ni) {
      int col = n0 + wc + ni * 16 + lr;
      float bb = bp[col];
      #pragma unroll
      for (int j = 0; j < 4; ++j) {
        int row = m0 + wr + mi * 16 + lg * 4 + j;
        out[(size_t)row * 768 + col] = acc[mi][ni][j] + bb;
      }
    }
}

// ---------------- causal flash attention: 128-row blocks, 2 M-frags/wave ------
// grid 768; LPT dynamic tasks via atomic counter (tau = 31 - idx/24: longest
// first). Wave w: frag0 rows tau*128+w*16+lr, frag1 +64. Main loop [0,nt-1)
// has BOTH frags active (no divergence); last iteration peeled frag1-only.
// K/V LDS reads and staging amortized over 2 frags. O^T = V^T P^T; PV via
// 16x16x16 (P in-lane); defer-max THR=8 with -mx folded into QK C-init.

#define SMAX_FRAG(ST, MX, LS, OO, PB) do { \
    float _m0 = fmaxf(fmaxf(fmaxf(ST[0][0], ST[0][1]), ST[0][2]), ST[0][3]); \
    float _m1 = fmaxf(fmaxf(fmaxf(ST[1][0], ST[1][1]), ST[1][2]), ST[1][3]); \
    float _m2 = fmaxf(fmaxf(fmaxf(ST[2][0], ST[2][1]), ST[2][2]), ST[2][3]); \
    float _m3 = fmaxf(fmaxf(fmaxf(ST[3][0], ST[3][1]), ST[3][2]), ST[3][3]); \
    float _vm = fmaxf(fmaxf(_m0, _m1), fmaxf(_m2, _m3)); \
    _vm = fmaxf(_vm, __shfl_xor(_vm, 16)); \
    _vm = fmaxf(_vm, __shfl_xor(_vm, 32)); \
    if (__any(_vm > 8.0f)) { \
      const float _g = fmaxf(_vm, 0.0f); \
      const float _co = exp2f(-_g); \
      MX += _g; LS *= _co; \
      OO[0] *= _co; OO[1] *= _co; OO[2] *= _co; OO[3] *= _co; \
      _Pragma("unroll") for (int _c = 0; _c < 4; ++_c) { \
        ST[_c][0] -= _g; ST[_c][1] -= _g; ST[_c][2] -= _g; ST[_c][3] -= _g; } \
    } \
    float _rs = 0.f; \
    _Pragma("unroll") for (int _c = 0; _c < 4; ++_c) { \
      float _p0 = exp2f(ST[_c][0]); float _p1 = exp2f(ST[_c][1]); \
      float _p2 = exp2f(ST[_c][2]); float _p3 = exp2f(ST[_c][3]); \
      _rs += (_p0 + _p1) + (_p2 + _p3); \
      PB[_c].u[0] = pack2(_p0, _p1); PB[_c].u[1] = pack2(_p2, _p3); } \
    _rs += __shfl_xor(_rs, 16); \
    _rs += __shfl_xor(_rs, 32); \
    LS += _rs; \
  } while (0)

#define MASK_FRAG(ST, QR, KT) do { \
    const int _kb = (KT) * 64; \
    _Pragma("unroll") for (int _c = 0; _c < 4; ++_c) \
      _Pragma("unroll") for (int _j = 0; _j < 4; ++_j) \
        if (_kb + _c * 16 + lg * 4 + _j > (QR)) ST[_c][_j] = -1e30f; \
  } while (0)

#define VOFFD(KS, CC) const int vo_##KS##_##CC = \
    ((CC) * 16 + lr) * 64 + (((2 * (KS) + (lg >> 1)) ^ (lr & 7)) * 8) + (lg & 1) * 4;

#define PV2(KS, CC) { short4b _va = *(const short4b*)(_vb + vo_##KS##_##CC); \
    o1[CC] = mfma16(_va, pb1[KS].s4, o1[CC]); \
    o0[CC] = mfma16(_va, pb0[KS].s4, o0[CC]); }
#define PV1(KS, CC) { short4b _va = *(const short4b*)(_vb + vo_##KS##_##CC); \
    o1[CC] = mfma16(_va, pb1[KS].s4, o1[CC]); }

__global__ __launch_bounds__(256) void k_attn(
    const ushort* __restrict__ q, const ushort* __restrict__ k,
    const ushort* __restrict__ vt, ushort* __restrict__ y,
    unsigned* __restrict__ ctr) {
  __shared__ __align__(16) ushort Ks[2][64 * 64];
  __shared__ __align__(16) ushort Vs[2][64 * 64];
  __shared__ unsigned task_s;
  const int tid = threadIdx.x, l = tid & 63, w = tid >> 6;
  const int lr = l & 15, lg = l >> 4;
  if (tid == 0) task_s = atomicAdd(ctr, 1u);
  __syncthreads();
  const int idx = (int)task_s;
  const int tau = 31 - idx / 24;          // LPT: longest tasks pulled first
  const int bh = idx % 24;
  const size_t kpl = (size_t)bh * T_ * 64;
  const size_t vpl = (size_t)bh * 64 * T_;
  const int nt = 2 * tau + 2;
  const int qr0 = tau * 128 + w * 16 + lr;
  const int qr1 = qr0 + 64;

  // Q fragments (B operand: col=q=lr, k = d)
  short8 qf0[2], qf1[2];
  #pragma unroll
  for (int kk = 0; kk < 2; ++kk) {
    qf0[kk] = *(const short8*)(q + kpl + (size_t)qr0 * 64 + kk * 32 + lg * 8);
    qf1[kk] = *(const short8*)(q + kpl + (size_t)qr1 * 64 + kk * 32 + lg * 8);
  }

  f32x4 o0[4], o1[4];
  float mx0 = 0.f, ls0 = 0.f, mx1 = 0.f, ls1 = 0.f;
  #pragma unroll
  for (int c = 0; c < 4; ++c) { o0[c] = (f32x4){0,0,0,0}; o1[c] = (f32x4){0,0,0,0}; }

  // hoisted lane-constant offsets
  const int kro0 = lr * 64 + ((lg ^ (lr & 7)) * 8);
  const int kro1 = lr * 64 + (((4 + lg) ^ (lr & 7)) * 8);
  VOFFD(0,0) VOFFD(0,1) VOFFD(0,2) VOFFD(0,3)
  VOFFD(1,0) VOFFD(1,1) VOFFD(1,2) VOFFD(1,3)
  VOFFD(2,0) VOFFD(2,1) VOFFD(2,2) VOFFD(2,3)
  VOFFD(3,0) VOFFD(3,1) VOFFD(3,2) VOFFD(3,3)

  // staging lane geometry (strength-reduced global pointers)
  const int r0 = w * 16 + (l >> 3);
  const int r1 = r0 + 8;
  const int c8 = (l & 7) * 8;
  const int wo0 = r0 * 64 + (c8 ^ ((r0 & 7) * 8));
  const int wo1 = r1 * 64 + (c8 ^ ((r1 & 7) * 8));
  const ushort* kg0 = k + kpl + (size_t)r0 * 64 + c8;
  const ushort* kg1 = k + kpl + (size_t)r1 * 64 + c8;
  const ushort* vg0 = vt + vpl + (size_t)r0 * T_ + c8;
  const ushort* vg1 = vt + vpl + (size_t)r1 * T_ + c8;

  // prologue: stage tile 0 -> buf 0
  *(short8*)&Ks[0][wo0] = *(const short8*)kg0;
  *(short8*)&Ks[0][wo1] = *(const short8*)kg1;
  *(short8*)&Vs[0][wo0] = *(const short8*)vg0;
  *(short8*)&Vs[0][wo1] = *(const short8*)vg1;
  kg0 += 64 * 64; kg1 += 64 * 64; vg0 += 64; vg1 += 64;

  int buf = 0;
  for (int kt = 0; kt < nt - 1; ++kt) {     // BOTH frags active on every iter
    __syncthreads();
    // issue next tile's loads (tile kt+1 <= nt-1 always exists here)
    short8 sk0 = *(const short8*)kg0;
    short8 sk1 = *(const short8*)kg1;
    short8 sv0 = *(const short8*)vg0;
    short8 sv1 = *(const short8*)vg1;
    kg0 += 64 * 64; kg1 += 64 * 64; vg0 += 64; vg1 += 64;

    // ---- S^T = K·Q - mx (both frags; kf shared) ----
    f32x4 sT0[4], sT1[4];
    {
      const ushort* _kb = &Ks[buf][0];
      #pragma unroll
      for (int c = 0; c < 4; ++c) {
        short8 kf0 = *(const short8*)(_kb + kro0 + c * 1024);
        short8 kf1 = *(const short8*)(_kb + kro1 + c * 1024);
        f32x4 z1 = (f32x4){-mx1, -mx1, -mx1, -mx1};
        z1 = mfma32(kf0, qf1[0], z1);
        z1 = mfma32(kf1, qf1[1], z1);
        sT1[c] = z1;
        f32x4 z0 = (f32x4){-mx0, -mx0, -mx0, -mx0};
        z0 = mfma32(kf0, qf0[0], z0);
        z0 = mfma32(kf1, qf0[1], z0);
        sT0[c] = z0;
      }
    }
    if (kt == nt - 2) MASK_FRAG(sT0, qr0, kt);   // frag0 diagonal = last main iter

    // ---- softmax both frags (lane-local) ----
    U32x2 pb0[4], pb1[4];
    SMAX_FRAG(sT1, mx1, ls1, o1, pb1);
    SMAX_FRAG(sT0, mx0, ls0, o0, pb0);

    // ---- PV both frags (va shared) ----
    __builtin_amdgcn_s_setprio(1);
    {
      const ushort* _vb = &Vs[buf][0];
      PV2(0,0) PV2(0,1) PV2(0,2) PV2(0,3)
      PV2(1,0) PV2(1,1) PV2(1,2) PV2(1,3)
      PV2(2,0) PV2(2,1) PV2(2,2) PV2(2,3)
      PV2(3,0) PV2(3,1) PV2(3,2) PV2(3,3)
    }
    __builtin_amdgcn_s_setprio(0);

    // write staged tile -> other buffer
    {
      ushort* _kd = &Ks[buf ^ 1][0];
      ushort* _vd = &Vs[buf ^ 1][0];
      *(short8*)(_kd + wo0) = sk0;
      *(short8*)(_kd + wo1) = sk1;
      *(short8*)(_vd + wo0) = sv0;
      *(short8*)(_vd + wo1) = sv1;
    }
    buf ^= 1;
  }

  // ---- peeled final iteration: frag1 only (its diagonal tile) ----
  {
    __syncthreads();
    const int kt = nt - 1;
    f32x4 sT1[4];
    {
      const ushort* _kb = &Ks[buf][0];
      #pragma unroll
      for (int c = 0; c < 4; ++c) {
        short8 kf0 = *(const short8*)(_kb + kro0 + c * 1024);
        short8 kf1 = *(const short8*)(_kb + kro1 + c * 1024);
        f32x4 z1 = (f32x4){-mx1, -mx1, -mx1, -mx1};
        z1 = mfma32(kf0, qf1[0], z1);
        z1 = mfma32(kf1, qf1[1], z1);
        sT1[c] = z1;
      }
    }
    MASK_FRAG(sT1, qr1, kt);
    U32x2 pb1[4];
    SMAX_FRAG(sT1, mx1, ls1, o1, pb1);
    __builtin_amdgcn_s_setprio(1);
    {
      const ushort* _vb = &Vs[buf][0];
      PV1(0,0) PV1(0,1) PV1(0,2) PV1(0,3)
      PV1(1,0) PV1(1,1) PV1(1,2) PV1(1,3)
      PV1(2,0) PV1(2,1) PV1(2,2) PV1(2,3)
      PV1(3,0) PV1(3,1) PV1(3,2) PV1(3,3)
    }
    __builtin_amdgcn_s_setprio(0);
  }

  // epilogue: normalize + write y [B,T,C]; O^T frag: col q=lr, row d=c*16+lg*4+j
  const int b = bh / H_, h = bh % H_;
  {
    const float li0 = 1.0f / ls0;
    const size_t base0 = ((size_t)b * T_ + qr0) * C_ + h * 64;
    const float li1 = 1.0f / ls1;
    const size_t base1 = ((size_t)b * T_ + qr1) * C_ + h * 64;
    #pragma unroll
    for (int c = 0; c < 4; ++c) {
      ushort4 p0, p1;
      p0.x = f2bf(o0[c][0] * li0); p0.y = f2bf(o0[c][1] * li0);
      p0.z = f2bf(o0[c][2] * li0); p0.w = f2bf(o0[c][3] * li0);
      p1.x = f2bf(o1[c][0] * li1); p1.y = f2bf(o1[c][1] * li1);
      p1.z = f2bf(o1[c][2] * li1); p1.w = f2bf(o1[c][3] * li1);
      *(ushort4*)(y + base0 + c * 16 + lg * 4) = p0;
      *(ushort4*)(y + base1 + c * 16 + lg * 4) = p1;
    }
  }
}

extern "C" void kernel_launch(void* const* d_in, const int* in_sizes, int n_in,
                              void* d_out, int out_size, void* d_ws, size_t ws_size,
                              hipStream_t stream) {
  const float* x  = (const float*)d_in[0];
  const float* Wq = (const float*)d_in[1];
  const float* bq = (const float*)d_in[2];
  const float* Wk = (const float*)d_in[3];
  const float* bk = (const float*)d_in[4];
  const float* Wv = (const float*)d_in[5];
  const float* bv = (const float*)d_in[6];
  const float* Wp = (const float*)d_in[7];
  const float* bp = (const float*)d_in[8];
  float* out = (float*)d_out;

  char* p = (char*)d_ws;
  auto alloc = [&](size_t bytes) { char* r = p; p += (bytes + 255) & ~255ULL; return r; };
  ushort* xb  = (ushort*)alloc((size_t)BT_ * C_ * 2);
  ushort* wqb = (ushort*)alloc((size_t)C_ * C_ * 2);
  ushort* wkb = (ushort*)alloc((size_t)C_ * C_ * 2);
  ushort* wvb = (ushort*)alloc((size_t)C_ * C_ * 2);
  ushort* wpb = (ushort*)alloc((size_t)C_ * C_ * 2);
  ushort* qb  = (ushort*)alloc((size_t)BT_ * C_ * 2);
  ushort* kb  = (ushort*)alloc((size_t)BT_ * C_ * 2);
  ushort* vtb = (ushort*)alloc((size_t)BT_ * C_ * 2);   // V^T [B,H,64,T]
  ushort* yb  = (ushort*)alloc((size_t)BT_ * C_ * 2);
  float* ctab = (float*)alloc((size_t)T_ * 32 * 4);
  float* stab = (float*)alloc((size_t)T_ * 32 * 4);
  unsigned* ctr = (unsigned*)alloc(256);

  k_f32_to_bf16<<<(BT_ * C_ / 4 + 255) / 256, 256, 0, stream>>>(x, xb, BT_ * C_ / 4);
  k_w_to_bf16<<<dim3((C_ * C_ / 4 + 255) / 256, 4), 256, 0, stream>>>(
      Wq, Wk, Wv, Wp, wqb, wkb, wvb, wpb, C_ * C_ / 4);
  k_rope_tab<<<T_ * 32 / 256, 256, 0, stream>>>(ctab, stab, ctr);

  k_qkv_gemm<<<dim3(BT_ / 128, 2304 / 128), 256, 0, stream>>>(
      xb, wqb, wkb, wvb, bq, bk, bv, qb, kb, vtb);

  k_rope_qk<<<dim3((B_ * H_ * T_ * 32) / 256, 2), 256, 0, stream>>>(qb, kb, ctab, stab);

  k_attn<<<dim3(768), 256, 0, stream>>>(qb, kb, vtb, yb, ctr);

  k_proj_gemm<<<dim3(BT_ / 128, C_ / 128), 256, 0, stream>>>(yb, wpb, bp, out);
}

// Round 11
// 254.342 us; speedup vs baseline: 1.0128x; 1.0128x over previous
//
#include <hip/hip_runtime.h>
#include <hip/hip_bf16.h>

#define B_  2
#define T_  4096
#define C_  768
#define H_  12
#define D_  64
#define BT_ (B_*T_)   // 8192

typedef __attribute__((ext_vector_type(8))) short short8;
typedef __attribute__((ext_vector_type(4))) short short4b;
typedef __attribute__((ext_vector_type(4))) float f32x4;

union U32x2 { unsigned u[2]; short4b s4; };

__device__ __forceinline__ ushort f2bf(float f) {
  union { __hip_bfloat16 b; ushort u; } cv; cv.b = __float2bfloat16(f); return cv.u;
}
__device__ __forceinline__ float bf2f(ushort u) {
  unsigned x = ((unsigned)u) << 16; float f; __builtin_memcpy(&f, &x, 4); return f;
}
// compiler-friendly pack (clang fuses to v_cvt_pk_bf16_f32)
__device__ __forceinline__ unsigned pack2(float a, float b) {
  return (unsigned)f2bf(a) | ((unsigned)f2bf(b) << 16);
}

// 16x16x16 bf16 MFMA (K=16, A/B k-granule = lg*4+i) — builtin-name guarded.
__device__ __forceinline__ f32x4 mfma16(short4b a, short4b b, f32x4 c) {
#if __has_builtin(__builtin_amdgcn_mfma_f32_16x16x16bf16_1k)
  return __builtin_amdgcn_mfma_f32_16x16x16bf16_1k(a, b, c, 0, 0, 0);
#elif __has_builtin(__builtin_amdgcn_mfma_f32_16x16x16_bf16)
  return __builtin_amdgcn_mfma_f32_16x16x16_bf16(a, b, c, 0, 0, 0);
#else
  asm("v_mfma_f32_16x16x16_bf16 %0, %1, %2, %0" : "+v"(c) : "v"(a), "v"(b));
  return c;
#endif
}

// ---------------- elementwise converts ----------------
__global__ void k_f32_to_bf16(const float* __restrict__ in, ushort* __restrict__ out, int n4) {
  int i = blockIdx.x * blockDim.x + threadIdx.x;
  if (i >= n4) return;
  const float4 v = ((const float4*)in)[i];
  ushort4 o;
  o.x = f2bf(v.x); o.y = f2bf(v.y); o.z = f2bf(v.z); o.w = f2bf(v.w);
  ((ushort4*)out)[i] = o;
}

// all four weight matrices in one launch (blockIdx.y selects)
__global__ void k_w_to_bf16(const float* __restrict__ w0, const float* __restrict__ w1,
                            const float* __restrict__ w2, const float* __restrict__ w3,
                            ushort* __restrict__ o0, ushort* __restrict__ o1,
                            ushort* __restrict__ o2, ushort* __restrict__ o3, int n4) {
  int i = blockIdx.x * blockDim.x + threadIdx.x;
  if (i >= n4) return;
  const int sel = blockIdx.y;
  const float* in = sel == 0 ? w0 : (sel == 1 ? w1 : (sel == 2 ? w2 : w3));
  ushort* out = sel == 0 ? o0 : (sel == 1 ? o1 : (sel == 2 ? o2 : o3));
  const float4 v = ((const float4*)in)[i];
  ushort4 o;
  o.x = f2bf(v.x); o.y = f2bf(v.y); o.z = f2bf(v.z); o.w = f2bf(v.w);
  ((ushort4*)out)[i] = o;
}

__global__ void k_rope_tab(float* __restrict__ ctab, float* __restrict__ stab) {
  int i = blockIdx.x * blockDim.x + threadIdx.x;  // T_*32 threads
  int t = i >> 5, p = i & 31;
  float inv = 1.0f / powf(10000.0f, (2.0f * (float)p) / 64.0f);
  float a = (float)t * inv;
  ctab[i] = cosf(a); stab[i] = sinf(a);
}

// ---------------- QKV projection GEMM (RoPE fused into q/k epilogue) ----------
// q,k -> [B,H,T,64] with RoPE applied (q also scaled by log2(e)/8);
// v -> TRANSPOSED [B,H,64,T] (attn consumes V^T fragments).
__global__ __launch_bounds__(256) void k_qkv_gemm(
    const ushort* __restrict__ xb, const ushort* __restrict__ wq,
    const ushort* __restrict__ wk, const ushort* __restrict__ wv,
    const float* __restrict__ bq, const float* __restrict__ bk, const float* __restrict__ bv,
    const float* __restrict__ ctab, const float* __restrict__ stab,
    ushort* __restrict__ qo, ushort* __restrict__ ko, ushort* __restrict__ vo) {
  __shared__ __align__(16) ushort As[128 * 72];
  __shared__ __align__(16) ushort Bs[128 * 72];
  const int tid = threadIdx.x, l = tid & 63, w = tid >> 6;
  const int lr = l & 15, lg = l >> 4;
  const int m0 = blockIdx.x * 128;
  const int n0g = blockIdx.y * 128;
  const int proj = n0g / 768;
  const int n0 = n0g % 768;
  const ushort* wsrc = proj == 0 ? wq : (proj == 1 ? wk : wv);
  const int wr = (w >> 1) * 64, wc = (w & 1) * 64;

  f32x4 acc[4][4];
  #pragma unroll
  for (int a = 0; a < 4; ++a)
    #pragma unroll
    for (int b = 0; b < 4; ++b) acc[a][b] = (f32x4){0.f, 0.f, 0.f, 0.f};

  for (int k0 = 0; k0 < 768; k0 += 64) {
    #pragma unroll
    for (int i = 0; i < 4; ++i) {
      int seg = tid + i * 256;
      int row = seg >> 3, c8 = (seg & 7) << 3;
      *(short8*)&As[row * 72 + c8] = *(const short8*)(xb + (size_t)(m0 + row) * 768 + k0 + c8);
      *(short8*)&Bs[row * 72 + c8] = *(const short8*)(wsrc + (size_t)(n0 + row) * 768 + k0 + c8);
    }
    __syncthreads();
    #pragma unroll
    for (int kk = 0; kk < 2; ++kk) {
      short8 af[4], bf[4];
      #pragma unroll
      for (int mi = 0; mi < 4; ++mi)
        af[mi] = *(const short8*)&As[(wr + mi * 16 + lr) * 72 + kk * 32 + lg * 8];
      #pragma unroll
      for (int ni = 0; ni < 4; ++ni)
        bf[ni] = *(const short8*)&Bs[(wc + ni * 16 + lr) * 72 + kk * 32 + lg * 8];
      #pragma unroll
      for (int mi = 0; mi < 4; ++mi)
        #pragma unroll
        for (int ni = 0; ni < 4; ++ni)
          acc[mi][ni] = __builtin_amdgcn_mfma_f32_16x16x32_bf16(af[mi], bf[ni], acc[mi][ni], 0, 0, 0);
    }
    __syncthreads();
  }

  const float* bias = proj == 0 ? bq : (proj == 1 ? bk : bv);
  if (proj == 2) {
    #pragma unroll
    for (int mi = 0; mi < 4; ++mi) {
      #pragma unroll
      for (int ni = 0; ni < 4; ++ni) {
        int colc = n0 + wc + ni * 16 + lr;
        float bb = bias[colc];
        int h = colc >> 6, d = colc & 63;
        int row0 = m0 + wr + mi * 16 + lg * 4;
        int b = row0 >> 12, t0 = row0 & (T_ - 1);
        ushort4 pk;
        pk.x = f2bf(acc[mi][ni][0] + bb);
        pk.y = f2bf(acc[mi][ni][1] + bb);
        pk.z = f2bf(acc[mi][ni][2] + bb);
        pk.w = f2bf(acc[mi][ni][3] + bb);
        *(ushort4*)(vo + (((size_t)b * H_ + h) * 64 + d) * T_ + t0) = pk;
      }
    }
  } else {
    // fused RoPE epilogue: d-pair partner lives in adjacent lane (lr^1).
    // even d: out = x_e*cos - x_o*sin ; odd d: out = x_e*sin + x_o*cos
    ushort* dst = proj == 0 ? qo : ko;
    const float qs = proj == 0 ? 0.18033688011112042f : 1.0f;   // log2(e)/8
    #pragma unroll
    for (int mi = 0; mi < 4; ++mi) {
      #pragma unroll
      for (int ni = 0; ni < 4; ++ni) {
        int colc = n0 + wc + ni * 16 + lr;
        float bb = bias[colc];
        int h = colc >> 6, d = colc & 63;
        const int pidx = d >> 1;
        const bool evn = (d & 1) == 0;
        #pragma unroll
        for (int j = 0; j < 4; ++j) {
          int row = m0 + wr + mi * 16 + lg * 4 + j;
          int b = row >> 12, t = row & (T_ - 1);
          float val = acc[mi][ni][j] + bb;          // biased (rope is post-bias)
          float prt = __shfl_xor(val, 1);           // partner d^1 (lane lr^1)
          float cc = ctab[(t << 5) + pidx];
          float ss = stab[(t << 5) + pidx];
          float ro = evn ? (val * cc - prt * ss) : (prt * ss + val * cc);
          dst[((((size_t)b * H_ + h) << 12) + t) * 64 + d] = f2bf(ro * qs);
        }
      }
    }
  }
}

// ---------------- output projection GEMM (f32 out) ----------------
__global__ __launch_bounds__(256) void k_proj_gemm(
    const ushort* __restrict__ yb, const ushort* __restrict__ wp,
    const float* __restrict__ bp, float* __restrict__ out) {
  __shared__ __align__(16) ushort As[128 * 72];
  __shared__ __align__(16) ushort Bs[128 * 72];
  const int tid = threadIdx.x, l = tid & 63, w = tid >> 6;
  const int lr = l & 15, lg = l >> 4;
  const int m0 = blockIdx.x * 128;
  const int n0 = blockIdx.y * 128;
  const int wr = (w >> 1) * 64, wc = (w & 1) * 64;

  f32x4 acc[4][4];
  #pragma unroll
  for (int a = 0; a < 4; ++a)
    #pragma unroll
    for (int b = 0; b < 4; ++b) acc[a][b] = (f32x4){0.f, 0.f, 0.f, 0.f};

  for (int k0 = 0; k0 < 768; k0 += 64) {
    #pragma unroll
    for (int i = 0; i < 4; ++i) {
      int seg = tid + i * 256;
      int row = seg >> 3, c8 = (seg & 7) << 3;
      *(short8*)&As[row * 72 + c8] = *(const short8*)(yb + (size_t)(m0 + row) * 768 + k0 + c8);
      *(short8*)&Bs[row * 72 + c8] = *(const short8*)(wp + (size_t)(n0 + row) * 768 + k0 + c8);
    }
    __syncthreads();
    #pragma unroll
    for (int kk = 0; kk < 2; ++kk) {
      short8 af[4], bf[4];
      #pragma unroll
      for (int mi = 0; mi < 4; ++mi)
        af[mi] = *(const short8*)&As[(wr + mi * 16 + lr) * 72 + kk * 32 + lg * 8];
      #pragma unroll
      for (int ni = 0; ni < 4; ++ni)
        bf[ni] = *(const short8*)&Bs[(wc + ni * 16 + lr) * 72 + kk * 32 + lg * 8];
      #pragma unroll
      for (int mi = 0; mi < 4; ++mi)
        #pragma unroll
        for (int ni = 0; ni < 4; ++ni)
          acc[mi][ni] = __builtin_amdgcn_mfma_f32_16x16x32_bf16(af[mi], bf[ni], acc[mi][ni], 0, 0, 0);
    }
    __syncthreads();
  }

  #pragma unroll
  for (int mi = 0; mi < 4; ++mi)
    #pragma unroll
    for (int ni = 0; ni < 4; ++ni) {
      int col = n0 + wc + ni * 16 + lr;
      float bb = bp[col];
      #pragma unroll
      for (int j = 0; j < 4; ++j) {
        int row = m0 + wr + mi * 16 + lg * 4 + j;
        out[(size_t)row * 768 + col] = acc[mi][ni][j] + bb;
      }
    }
}

// ---------------- causal flash attention: one 64-row q-tile per block ----------
// grid 1536. XCD-clustered mapping (T1): x=bid&7 selects XCD cluster; the 3 bh
// planes {x, x+8, x+16} (3 MB K/V) stay XCD-L2-resident. Balanced snake tiles:
// i=j/3, t = (i&1) ? 63-(i>>1) : (i>>1). O^T = V^T P^T (lane-local softmax
// state), PV via 16x16x16 (P in-lane), defer-max THR=8 with -mx folded into
// QK C-init. K double-buffered, V single-buffered (24 KB LDS, 2 barriers).
__global__ __launch_bounds__(256) void k_attn(
    const ushort* __restrict__ q, const ushort* __restrict__ k,
    const ushort* __restrict__ vt, ushort* __restrict__ y) {
  __shared__ __align__(16) ushort Ks[2][64 * 64];
  __shared__ __align__(16) ushort Vs[64 * 64];
  const int tid = threadIdx.x, l = tid & 63, w = tid >> 6;
  const int lr = l & 15, lg = l >> 4;
  const int bid = blockIdx.x;
  const int x = bid & 7, j = bid >> 3;        // j in [0,192)
  const int bh = x + 8 * (j % 3);             // XCD-clustered bh
  const int i = j / 3;                        // 0..63, balanced snake
  const int t = (i & 1) ? 63 - (i >> 1) : (i >> 1);
  const size_t kpl = (size_t)bh * T_ * 64;
  const size_t vpl = (size_t)bh * 64 * T_;
  const int qrow = t * 64 + w * 16 + lr;
  const int nt = t + 1;

  // Q fragments (B operand of S^T = K·Q: col=q=lane&15, k-rows = d)
  short8 qf[2];
  #pragma unroll
  for (int kk = 0; kk < 2; ++kk)
    qf[kk] = *(const short8*)(q + kpl + (size_t)qrow * 64 + kk * 32 + lg * 8);

  f32x4 o[4];
  float mx = 0.0f, ls = 0.f;   // mx=0 init: shift-invariant, keeps C-fold f32-exact
  #pragma unroll
  for (int c = 0; c < 4; ++c) o[c] = (f32x4){0.f, 0.f, 0.f, 0.f};

  // prologue: stage tile 0 (XOR-swizzled 16B slots)
  {
    #pragma unroll
    for (int i2 = 0; i2 < 2; ++i2) {
      const int r = w * 16 + i2 * 8 + (l >> 3);
      const int sl = (l & 7) ^ (r & 7);
      short8 s0 = *(const short8*)(k + kpl + (size_t)r * 64 + (l & 7) * 8);
      short8 v0 = *(const short8*)(vt + vpl + (size_t)r * T_ + (l & 7) * 8);
      *(short8*)&Ks[0][r * 64 + sl * 8] = s0;
      *(short8*)&Vs[r * 64 + sl * 8] = v0;
    }
  }

  int buf = 0;
  for (int kt = 0; kt < nt; ++kt) {
    __syncthreads();   // (A) staged K[buf]/V visible
    // async-split staging: issue next tile's global loads before compute
    short8 sk[2], sv[2];
    const bool pre = (kt + 1 < nt);
    if (pre) {
      #pragma unroll
      for (int i2 = 0; i2 < 2; ++i2) {
        const int r = w * 16 + i2 * 8 + (l >> 3);
        sk[i2] = *(const short8*)(k + kpl + (size_t)((kt + 1) * 64 + r) * 64 + (l & 7) * 8);
        sv[i2] = *(const short8*)(vt + vpl + (size_t)r * T_ + (kt + 1) * 64 + (l & 7) * 8);
      }
    }

    // ---- S^T = K·Q - mx (shift folded into MFMA C-init) ----
    const f32x4 zinit = (f32x4){-mx, -mx, -mx, -mx};
    f32x4 sT[4];
    #pragma unroll
    for (int c = 0; c < 4; ++c) {
      short8 kf0 = *(const short8*)&Ks[buf][(c * 16 + lr) * 64 + ((lg) ^ (lr & 7)) * 8];
      short8 kf1 = *(const short8*)&Ks[buf][(c * 16 + lr) * 64 + ((4 + lg) ^ (lr & 7)) * 8];
      f32x4 z = zinit;
      z = __builtin_amdgcn_mfma_f32_16x16x32_bf16(kf0, qf[0], z, 0, 0, 0);
      z = __builtin_amdgcn_mfma_f32_16x16x32_bf16(kf1, qf[1], z, 0, 0, 0);
      sT[c] = z;
    }

    // ---- softmax (lane-local state, q = lr); sT is RELATIVE to mx ----
    if (kt == t) {   // diagonal tile: causal mask (S^T row=key, col=q)
      #pragma unroll
      for (int c = 0; c < 4; ++c)
        #pragma unroll
        for (int jj = 0; jj < 4; ++jj)
          if (kt * 64 + c * 16 + lg * 4 + jj > qrow) sT[c][jj] = -1e30f;
    }
    float cm0 = fmaxf(fmaxf(fmaxf(sT[0][0], sT[0][1]), sT[0][2]), sT[0][3]);
    float cm1 = fmaxf(fmaxf(fmaxf(sT[1][0], sT[1][1]), sT[1][2]), sT[1][3]);
    float cm2 = fmaxf(fmaxf(fmaxf(sT[2][0], sT[2][1]), sT[2][2]), sT[2][3]);
    float cm3 = fmaxf(fmaxf(fmaxf(sT[3][0], sT[3][1]), sT[3][2]), sT[3][3]);
    float vmax = fmaxf(fmaxf(fmaxf(cm0, cm1), cm2), cm3);
    vmax = fmaxf(vmax, __shfl_xor(vmax, 16));
    vmax = fmaxf(vmax, __shfl_xor(vmax, 32));
    // T13 defer-max: rescale only when relative growth exceeds THR=8
    if (__any(vmax > 8.0f)) {
      const float g = fmaxf(vmax, 0.0f);
      const float corr = exp2f(-g);
      mx += g;
      ls *= corr;
      #pragma unroll
      for (int c = 0; c < 4; ++c) o[c] *= corr;
      #pragma unroll
      for (int c = 0; c < 4; ++c)
        #pragma unroll
        for (int jj = 0; jj < 4; ++jj) sT[c][jj] -= g;
    }
    // common path: p = exp2(sT) directly — no subtraction
    float rs = 0.f;
    U32x2 pb[4];
    #pragma unroll
    for (int c = 0; c < 4; ++c) {
      float p0 = exp2f(sT[c][0]);
      float p1 = exp2f(sT[c][1]);
      float p2 = exp2f(sT[c][2]);
      float p3 = exp2f(sT[c][3]);
      rs += (p0 + p1) + (p2 + p3);
      pb[c].u[0] = pack2(p0, p1); pb[c].u[1] = pack2(p2, p3);
    }
    rs += __shfl_xor(rs, 16);
    rs += __shfl_xor(rs, 32);
    ls += rs;

    // ---- O^T += V^T·P^T via 16x16x16 (P in-lane, no exchange) ----
    __builtin_amdgcn_s_setprio(1);
    #pragma unroll
    for (int ks = 0; ks < 4; ++ks) {
      #pragma unroll
      for (int c = 0; c < 4; ++c) {
        const int row = c * 16 + lr;
        const int sl = (2 * ks + (lg >> 1)) ^ (row & 7);
        short4b va = *(const short4b*)&Vs[row * 64 + sl * 8 + (lg & 1) * 4];
        o[c] = mfma16(va, pb[ks].s4, o[c]);
      }
    }
    __builtin_amdgcn_s_setprio(0);

    __syncthreads();   // (B) all waves done reading Vs before overwrite
    if (pre) {
      #pragma unroll
      for (int i2 = 0; i2 < 2; ++i2) {
        const int r = w * 16 + i2 * 8 + (l >> 3);
        const int sl = (l & 7) ^ (r & 7);
        *(short8*)&Ks[buf ^ 1][r * 64 + sl * 8] = sk[i2];
        *(short8*)&Vs[r * 64 + sl * 8] = sv[i2];
      }
    }
    buf ^= 1;
  }

  // epilogue: normalize (lane-local) + write y [B, T, C]; O^T frag: col q = lr,
  // row d = c*16 + lg*4 + j
  const int b = bh / H_, h = bh % H_;
  const float linv = 1.0f / ls;
  const size_t base = ((size_t)b * T_ + qrow) * C_ + h * 64;
  #pragma unroll
  for (int c = 0; c < 4; ++c) {
    ushort4 pk;
    pk.x = f2bf(o[c][0] * linv);
    pk.y = f2bf(o[c][1] * linv);
    pk.z = f2bf(o[c][2] * linv);
    pk.w = f2bf(o[c][3] * linv);
    *(ushort4*)(y + base + c * 16 + lg * 4) = pk;
  }
}

extern "C" void kernel_launch(void* const* d_in, const int* in_sizes, int n_in,
                              void* d_out, int out_size, void* d_ws, size_t ws_size,
                              hipStream_t stream) {
  const float* x  = (const float*)d_in[0];
  const float* Wq = (const float*)d_in[1];
  const float* bq = (const float*)d_in[2];
  const float* Wk = (const float*)d_in[3];
  const float* bk = (const float*)d_in[4];
  const float* Wv = (const float*)d_in[5];
  const float* bv = (const float*)d_in[6];
  const float* Wp = (const float*)d_in[7];
  const float* bp = (const float*)d_in[8];
  float* out = (float*)d_out;

  // ws: exact R3-proven footprint (~69 MB)
  char* p = (char*)d_ws;
  auto alloc = [&](size_t bytes) { char* r = p; p += (bytes + 255) & ~255ULL; return r; };
  ushort* xb  = (ushort*)alloc((size_t)BT_ * C_ * 2);
  ushort* wqb = (ushort*)alloc((size_t)C_ * C_ * 2);
  ushort* wkb = (ushort*)alloc((size_t)C_ * C_ * 2);
  ushort* wvb = (ushort*)alloc((size_t)C_ * C_ * 2);
  ushort* wpb = (ushort*)alloc((size_t)C_ * C_ * 2);
  ushort* qb  = (ushort*)alloc((size_t)BT_ * C_ * 2);
  ushort* kb  = (ushort*)alloc((size_t)BT_ * C_ * 2);
  ushort* vtb = (ushort*)alloc((size_t)BT_ * C_ * 2);   // V^T [B,H,64,T]
  ushort* yb  = (ushort*)alloc((size_t)BT_ * C_ * 2);
  float* ctab = (float*)alloc((size_t)T_ * 32 * 4);
  float* stab = (float*)alloc((size_t)T_ * 32 * 4);

  k_f32_to_bf16<<<(BT_ * C_ / 4 + 255) / 256, 256, 0, stream>>>(x, xb, BT_ * C_ / 4);
  k_w_to_bf16<<<dim3((C_ * C_ / 4 + 255) / 256, 4), 256, 0, stream>>>(
      Wq, Wk, Wv, Wp, wqb, wkb, wvb, wpb, C_ * C_ / 4);
  k_rope_tab<<<T_ * 32 / 256, 256, 0, stream>>>(ctab, stab);

  // QKV projection with fused RoPE (q scaled by log2(e)/8 for exp2-domain softmax)
  k_qkv_gemm<<<dim3(BT_ / 128, 2304 / 128), 256, 0, stream>>>(
      xb, wqb, wkb, wvb, bq, bk, bv, ctab, stab, qb, kb, vtb);

  k_attn<<<dim3(1536), 256, 0, stream>>>(qb, kb, vtb, yb);

  k_proj_gemm<<<dim3(BT_ / 128, C_ / 128), 256, 0, stream>>>(yb, wpb, bp, out);
}

// Round 12
// 218.952 us; speedup vs baseline: 1.1765x; 1.1616x over previous
//
#include <hip/hip_runtime.h>
#include <hip/hip_bf16.h>

#define B_  2
#define T_  4096
#define C_  768
#define H_  12
#define D_  64
#define BT_ (B_*T_)   // 8192

typedef __attribute__((ext_vector_type(8))) short short8;
typedef __attribute__((ext_vector_type(4))) short short4b;
typedef __attribute__((ext_vector_type(4))) float f32x4;

union U32x2 { unsigned u[2]; short4b s4; };

__device__ __forceinline__ ushort f2bf(float f) {
  union { __hip_bfloat16 b; ushort u; } cv; cv.b = __float2bfloat16(f); return cv.u;
}
__device__ __forceinline__ float bf2f(ushort u) {
  unsigned x = ((unsigned)u) << 16; float f; __builtin_memcpy(&f, &x, 4); return f;
}
// compiler-friendly pack (clang fuses to v_cvt_pk_bf16_f32)
__device__ __forceinline__ unsigned pack2(float a, float b) {
  return (unsigned)f2bf(a) | ((unsigned)f2bf(b) << 16);
}

// 16x16x16 bf16 MFMA (K=16, A/B k-granule = lg*4+i) — builtin-name guarded.
__device__ __forceinline__ f32x4 mfma16(short4b a, short4b b, f32x4 c) {
#if __has_builtin(__builtin_amdgcn_mfma_f32_16x16x16bf16_1k)
  return __builtin_amdgcn_mfma_f32_16x16x16bf16_1k(a, b, c, 0, 0, 0);
#elif __has_builtin(__builtin_amdgcn_mfma_f32_16x16x16_bf16)
  return __builtin_amdgcn_mfma_f32_16x16x16_bf16(a, b, c, 0, 0, 0);
#else
  asm("v_mfma_f32_16x16x16_bf16 %0, %1, %2, %0" : "+v"(c) : "v"(a), "v"(b));
  return c;
#endif
}

// ---------------- elementwise converts ----------------
__global__ void k_f32_to_bf16(const float* __restrict__ in, ushort* __restrict__ out, int n4) {
  int i = blockIdx.x * blockDim.x + threadIdx.x;
  if (i >= n4) return;
  const float4 v = ((const float4*)in)[i];
  ushort4 o;
  o.x = f2bf(v.x); o.y = f2bf(v.y); o.z = f2bf(v.z); o.w = f2bf(v.w);
  ((ushort4*)out)[i] = o;
}

// all four weight matrices in one launch (blockIdx.y selects)
__global__ void k_w_to_bf16(const float* __restrict__ w0, const float* __restrict__ w1,
                            const float* __restrict__ w2, const float* __restrict__ w3,
                            ushort* __restrict__ o0, ushort* __restrict__ o1,
                            ushort* __restrict__ o2, ushort* __restrict__ o3, int n4) {
  int i = blockIdx.x * blockDim.x + threadIdx.x;
  if (i >= n4) return;
  const int sel = blockIdx.y;
  const float* in = sel == 0 ? w0 : (sel == 1 ? w1 : (sel == 2 ? w2 : w3));
  ushort* out = sel == 0 ? o0 : (sel == 1 ? o1 : (sel == 2 ? o2 : o3));
  const float4 v = ((const float4*)in)[i];
  ushort4 o;
  o.x = f2bf(v.x); o.y = f2bf(v.y); o.z = f2bf(v.z); o.w = f2bf(v.w);
  ((ushort4*)out)[i] = o;
}

__global__ void k_rope_tab(float* __restrict__ ctab, float* __restrict__ stab) {
  int i = blockIdx.x * blockDim.x + threadIdx.x;  // T_*32 threads
  int t = i >> 5, p = i & 31;
  float inv = 1.0f / powf(10000.0f, (2.0f * (float)p) / 64.0f);
  float a = (float)t * inv;
  ctab[i] = cosf(a); stab[i] = sinf(a);
}

// ---------------- QKV projection GEMM (RoPE fused into q/k epilogue) ----------
// q,k -> [B,H,T,64] with RoPE applied (q also scaled by log2(e)/8);
// v -> TRANSPOSED [B,H,64,T] (attn consumes V^T fragments).
__global__ __launch_bounds__(256) void k_qkv_gemm(
    const ushort* __restrict__ xb, const ushort* __restrict__ wq,
    const ushort* __restrict__ wk, const ushort* __restrict__ wv,
    const float* __restrict__ bq, const float* __restrict__ bk, const float* __restrict__ bv,
    const float* __restrict__ ctab, const float* __restrict__ stab,
    ushort* __restrict__ qo, ushort* __restrict__ ko, ushort* __restrict__ vo) {
  __shared__ __align__(16) ushort As[128 * 72];
  __shared__ __align__(16) ushort Bs[128 * 72];
  const int tid = threadIdx.x, l = tid & 63, w = tid >> 6;
  const int lr = l & 15, lg = l >> 4;
  const int m0 = blockIdx.x * 128;
  const int n0g = blockIdx.y * 128;
  const int proj = n0g / 768;
  const int n0 = n0g % 768;
  const ushort* wsrc = proj == 0 ? wq : (proj == 1 ? wk : wv);
  const int wr = (w >> 1) * 64, wc = (w & 1) * 64;

  f32x4 acc[4][4];
  #pragma unroll
  for (int a = 0; a < 4; ++a)
    #pragma unroll
    for (int b = 0; b < 4; ++b) acc[a][b] = (f32x4){0.f, 0.f, 0.f, 0.f};

  for (int k0 = 0; k0 < 768; k0 += 64) {
    #pragma unroll
    for (int i = 0; i < 4; ++i) {
      int seg = tid + i * 256;
      int row = seg >> 3, c8 = (seg & 7) << 3;
      *(short8*)&As[row * 72 + c8] = *(const short8*)(xb + (size_t)(m0 + row) * 768 + k0 + c8);
      *(short8*)&Bs[row * 72 + c8] = *(const short8*)(wsrc + (size_t)(n0 + row) * 768 + k0 + c8);
    }
    __syncthreads();
    #pragma unroll
    for (int kk = 0; kk < 2; ++kk) {
      short8 af[4], bf[4];
      #pragma unroll
      for (int mi = 0; mi < 4; ++mi)
        af[mi] = *(const short8*)&As[(wr + mi * 16 + lr) * 72 + kk * 32 + lg * 8];
      #pragma unroll
      for (int ni = 0; ni < 4; ++ni)
        bf[ni] = *(const short8*)&Bs[(wc + ni * 16 + lr) * 72 + kk * 32 + lg * 8];
      #pragma unroll
      for (int mi = 0; mi < 4; ++mi)
        #pragma unroll
        for (int ni = 0; ni < 4; ++ni)
          acc[mi][ni] = __builtin_amdgcn_mfma_f32_16x16x32_bf16(af[mi], bf[ni], acc[mi][ni], 0, 0, 0);
    }
    __syncthreads();
  }

  const float* bias = proj == 0 ? bq : (proj == 1 ? bk : bv);
  if (proj == 2) {
    #pragma unroll
    for (int mi = 0; mi < 4; ++mi) {
      #pragma unroll
      for (int ni = 0; ni < 4; ++ni) {
        int colc = n0 + wc + ni * 16 + lr;
        float bb = bias[colc];
        int h = colc >> 6, d = colc & 63;
        int row0 = m0 + wr + mi * 16 + lg * 4;
        int b = row0 >> 12, t0 = row0 & (T_ - 1);
        ushort4 pk;
        pk.x = f2bf(acc[mi][ni][0] + bb);
        pk.y = f2bf(acc[mi][ni][1] + bb);
        pk.z = f2bf(acc[mi][ni][2] + bb);
        pk.w = f2bf(acc[mi][ni][3] + bb);
        *(ushort4*)(vo + (((size_t)b * H_ + h) * 64 + d) * T_ + t0) = pk;
      }
    }
  } else {
    // fused RoPE epilogue: d-pair partner lives in adjacent lane (lr^1).
    ushort* dst = proj == 0 ? qo : ko;
    const float qs = proj == 0 ? 0.18033688011112042f : 1.0f;   // log2(e)/8
    #pragma unroll
    for (int mi = 0; mi < 4; ++mi) {
      #pragma unroll
      for (int ni = 0; ni < 4; ++ni) {
        int colc = n0 + wc + ni * 16 + lr;
        float bb = bias[colc];
        int h = colc >> 6, d = colc & 63;
        const int pidx = d >> 1;
        const bool evn = (d & 1) == 0;
        #pragma unroll
        for (int j = 0; j < 4; ++j) {
          int row = m0 + wr + mi * 16 + lg * 4 + j;
          int b = row >> 12, t = row & (T_ - 1);
          float val = acc[mi][ni][j] + bb;          // biased (rope is post-bias)
          float prt = __shfl_xor(val, 1);           // partner d^1 (lane lr^1)
          float cc = ctab[(t << 5) + pidx];
          float ss = stab[(t << 5) + pidx];
          float ro = evn ? (val * cc - prt * ss) : (prt * ss + val * cc);
          dst[((((size_t)b * H_ + h) << 12) + t) * 64 + d] = f2bf(ro * qs);
        }
      }
    }
  }
}

// ---------------- output projection GEMM (f32 out) ----------------
__global__ __launch_bounds__(256) void k_proj_gemm(
    const ushort* __restrict__ yb, const ushort* __restrict__ wp,
    const float* __restrict__ bp, float* __restrict__ out) {
  __shared__ __align__(16) ushort As[128 * 72];
  __shared__ __align__(16) ushort Bs[128 * 72];
  const int tid = threadIdx.x, l = tid & 63, w = tid >> 6;
  const int lr = l & 15, lg = l >> 4;
  const int m0 = blockIdx.x * 128;
  const int n0 = blockIdx.y * 128;
  const int wr = (w >> 1) * 64, wc = (w & 1) * 64;

  f32x4 acc[4][4];
  #pragma unroll
  for (int a = 0; a < 4; ++a)
    #pragma unroll
    for (int b = 0; b < 4; ++b) acc[a][b] = (f32x4){0.f, 0.f, 0.f, 0.f};

  for (int k0 = 0; k0 < 768; k0 += 64) {
    #pragma unroll
    for (int i = 0; i < 4; ++i) {
      int seg = tid + i * 256;
      int row = seg >> 3, c8 = (seg & 7) << 3;
      *(short8*)&As[row * 72 + c8] = *(const short8*)(yb + (size_t)(m0 + row) * 768 + k0 + c8);
      *(short8*)&Bs[row * 72 + c8] = *(const short8*)(wp + (size_t)(n0 + row) * 768 + k0 + c8);
    }
    __syncthreads();
    #pragma unroll
    for (int kk = 0; kk < 2; ++kk) {
      short8 af[4], bf[4];
      #pragma unroll
      for (int mi = 0; mi < 4; ++mi)
        af[mi] = *(const short8*)&As[(wr + mi * 16 + lr) * 72 + kk * 32 + lg * 8];
      #pragma unroll
      for (int ni = 0; ni < 4; ++ni)
        bf[ni] = *(const short8*)&Bs[(wc + ni * 16 + lr) * 72 + kk * 32 + lg * 8];
      #pragma unroll
      for (int mi = 0; mi < 4; ++mi)
        #pragma unroll
        for (int ni = 0; ni < 4; ++ni)
          acc[mi][ni] = __builtin_amdgcn_mfma_f32_16x16x32_bf16(af[mi], bf[ni], acc[mi][ni], 0, 0, 0);
    }
    __syncthreads();
  }

  #pragma unroll
  for (int mi = 0; mi < 4; ++mi)
    #pragma unroll
    for (int ni = 0; ni < 4; ++ni) {
      int col = n0 + wc + ni * 16 + lr;
      float bb = bp[col];
      #pragma unroll
      for (int j = 0; j < 4; ++j) {
        int row = m0 + wr + mi * 16 + lg * 4 + j;
        out[(size_t)row * 768 + col] = acc[mi][ni][j] + bb;
      }
    }
}

// ---------------- causal flash attention: UNIFORM 65-iter blocks --------------
// grid 768: block (p = bid&31, bh = bid>>5) runs TWO sequential complete tiles:
//   phase A: tile p    (p+1 iters), phase B: tile 63-p (64-p iters) = 65 total.
// Every block identical duration -> 3 blocks/CU all-resident, all finish
// together (constant 12 waves/CU; no temporal drain). Each phase is the
// R6-proven loop: O^T = V^T P^T, PV via 16x16x16 (P in-lane), defer-max THR=8
// with -mx folded into QK C-init, K/V double-buffered 32KB LDS, 1 barrier/iter.
__global__ __launch_bounds__(256) void k_attn(
    const ushort* __restrict__ q, const ushort* __restrict__ k,
    const ushort* __restrict__ vt, ushort* __restrict__ y) {
  __shared__ __align__(16) ushort Ks[2][64 * 64];
  __shared__ __align__(16) ushort Vs[2][64 * 64];
  const int tid = threadIdx.x, l = tid & 63, w = tid >> 6;
  const int lr = l & 15, lg = l >> 4;
  const int p = blockIdx.x & 31;
  const int bh = blockIdx.x >> 5;
  const size_t kpl = (size_t)bh * T_ * 64;
  const size_t vpl = (size_t)bh * 64 * T_;
  const int b = bh / H_, h = bh % H_;

  #pragma unroll 1
  for (int ph = 0; ph < 2; ++ph) {
    const int t = ph == 0 ? p : 63 - p;
    const int nt = t + 1;
    const int qrow = t * 64 + w * 16 + lr;

    // Q fragments (B operand of S^T = K·Q: col=q=lane&15, k-rows = d)
    short8 qf[2];
    #pragma unroll
    for (int kk = 0; kk < 2; ++kk)
      qf[kk] = *(const short8*)(q + kpl + (size_t)qrow * 64 + kk * 32 + lg * 8);

    f32x4 o[4];
    float mx = 0.0f, ls = 0.f;  // mx=0 init: shift-invariant, keeps C-fold f32-exact
    #pragma unroll
    for (int c = 0; c < 4; ++c) o[c] = (f32x4){0.f, 0.f, 0.f, 0.f};

    __syncthreads();   // previous phase's LDS reads complete before re-staging
    // prologue: stage tile 0 into buf 0 (XOR-swizzled 16B slots)
    {
      #pragma unroll
      for (int i2 = 0; i2 < 2; ++i2) {
        const int r = w * 16 + i2 * 8 + (l >> 3);
        const int sl = (l & 7) ^ (r & 7);
        short8 s0 = *(const short8*)(k + kpl + (size_t)r * 64 + (l & 7) * 8);
        short8 v0 = *(const short8*)(vt + vpl + (size_t)r * T_ + (l & 7) * 8);
        *(short8*)&Ks[0][r * 64 + sl * 8] = s0;
        *(short8*)&Vs[0][r * 64 + sl * 8] = v0;
      }
    }

    int buf = 0;
    for (int kt = 0; kt < nt; ++kt) {
      __syncthreads();
      // async-split staging: issue next tile's global loads before compute
      short8 sk[2], sv[2];
      const bool pre = (kt + 1 < nt);
      if (pre) {
        #pragma unroll
        for (int i2 = 0; i2 < 2; ++i2) {
          const int r = w * 16 + i2 * 8 + (l >> 3);
          sk[i2] = *(const short8*)(k + kpl + (size_t)((kt + 1) * 64 + r) * 64 + (l & 7) * 8);
          sv[i2] = *(const short8*)(vt + vpl + (size_t)r * T_ + (kt + 1) * 64 + (l & 7) * 8);
        }
      }

      // ---- S^T = K·Q - mx (shift folded into MFMA C-init) ----
      const f32x4 zinit = (f32x4){-mx, -mx, -mx, -mx};
      f32x4 sT[4];
      #pragma unroll
      for (int c = 0; c < 4; ++c) {
        short8 kf0 = *(const short8*)&Ks[buf][(c * 16 + lr) * 64 + ((lg) ^ (lr & 7)) * 8];
        short8 kf1 = *(const short8*)&Ks[buf][(c * 16 + lr) * 64 + ((4 + lg) ^ (lr & 7)) * 8];
        f32x4 z = zinit;
        z = __builtin_amdgcn_mfma_f32_16x16x32_bf16(kf0, qf[0], z, 0, 0, 0);
        z = __builtin_amdgcn_mfma_f32_16x16x32_bf16(kf1, qf[1], z, 0, 0, 0);
        sT[c] = z;
      }

      // ---- softmax (lane-local state, q = lr); sT is RELATIVE to mx ----
      if (kt == t) {   // diagonal tile: causal mask (S^T row=key, col=q)
        #pragma unroll
        for (int c = 0; c < 4; ++c)
          #pragma unroll
          for (int jj = 0; jj < 4; ++jj)
            if (kt * 64 + c * 16 + lg * 4 + jj > qrow) sT[c][jj] = -1e30f;
      }
      float cm0 = fmaxf(fmaxf(fmaxf(sT[0][0], sT[0][1]), sT[0][2]), sT[0][3]);
      float cm1 = fmaxf(fmaxf(fmaxf(sT[1][0], sT[1][1]), sT[1][2]), sT[1][3]);
      float cm2 = fmaxf(fmaxf(fmaxf(sT[2][0], sT[2][1]), sT[2][2]), sT[2][3]);
      float cm3 = fmaxf(fmaxf(fmaxf(sT[3][0], sT[3][1]), sT[3][2]), sT[3][3]);
      float vmax = fmaxf(fmaxf(fmaxf(cm0, cm1), cm2), cm3);
      vmax = fmaxf(vmax, __shfl_xor(vmax, 16));
      vmax = fmaxf(vmax, __shfl_xor(vmax, 32));
      // T13 defer-max: rescale only when relative growth exceeds THR=8
      if (__any(vmax > 8.0f)) {
        const float g = fmaxf(vmax, 0.0f);
        const float corr = exp2f(-g);
        mx += g;
        ls *= corr;
        #pragma unroll
        for (int c = 0; c < 4; ++c) o[c] *= corr;
        #pragma unroll
        for (int c = 0; c < 4; ++c)
          #pragma unroll
          for (int jj = 0; jj < 4; ++jj) sT[c][jj] -= g;
      }
      // common path: p = exp2(sT) directly — no subtraction
      float rs = 0.f;
      U32x2 pb[4];
      #pragma unroll
      for (int c = 0; c < 4; ++c) {
        float p0 = exp2f(sT[c][0]);
        float p1 = exp2f(sT[c][1]);
        float p2 = exp2f(sT[c][2]);
        float p3 = exp2f(sT[c][3]);
        rs += (p0 + p1) + (p2 + p3);
        pb[c].u[0] = pack2(p0, p1); pb[c].u[1] = pack2(p2, p3);
      }
      rs += __shfl_xor(rs, 16);
      rs += __shfl_xor(rs, 32);
      ls += rs;

      // ---- O^T += V^T·P^T via 16x16x16 (P in-lane, no exchange) ----
      __builtin_amdgcn_s_setprio(1);
      #pragma unroll
      for (int ks = 0; ks < 4; ++ks) {
        #pragma unroll
        for (int c = 0; c < 4; ++c) {
          const int row = c * 16 + lr;
          const int sl = (2 * ks + (lg >> 1)) ^ (row & 7);
          short4b va = *(const short4b*)&Vs[buf][row * 64 + sl * 8 + (lg & 1) * 4];
          o[c] = mfma16(va, pb[ks].s4, o[c]);
        }
      }
      __builtin_amdgcn_s_setprio(0);

      if (pre) {
        #pragma unroll
        for (int i2 = 0; i2 < 2; ++i2) {
          const int r = w * 16 + i2 * 8 + (l >> 3);
          const int sl = (l & 7) ^ (r & 7);
          *(short8*)&Ks[buf ^ 1][r * 64 + sl * 8] = sk[i2];
          *(short8*)&Vs[buf ^ 1][r * 64 + sl * 8] = sv[i2];
        }
      }
      buf ^= 1;
    }

    // phase epilogue: normalize (lane-local) + write y [B, T, C]
    const float linv = 1.0f / ls;
    const size_t base = ((size_t)b * T_ + qrow) * C_ + h * 64;
    #pragma unroll
    for (int c = 0; c < 4; ++c) {
      ushort4 pk;
      pk.x = f2bf(o[c][0] * linv);
      pk.y = f2bf(o[c][1] * linv);
      pk.z = f2bf(o[c][2] * linv);
      pk.w = f2bf(o[c][3] * linv);
      *(ushort4*)(y + base + c * 16 + lg * 4) = pk;
    }
  }
}

extern "C" void kernel_launch(void* const* d_in, const int* in_sizes, int n_in,
                              void* d_out, int out_size, void* d_ws, size_t ws_size,
                              hipStream_t stream) {
  const float* x  = (const float*)d_in[0];
  const float* Wq = (const float*)d_in[1];
  const float* bq = (const float*)d_in[2];
  const float* Wk = (const float*)d_in[3];
  const float* bk = (const float*)d_in[4];
  const float* Wv = (const float*)d_in[5];
  const float* bv = (const float*)d_in[6];
  const float* Wp = (const float*)d_in[7];
  const float* bp = (const float*)d_in[8];
  float* out = (float*)d_out;

  // ws: exact R3-proven footprint (~69 MB)
  char* p = (char*)d_ws;
  auto alloc = [&](size_t bytes) { char* r = p; p += (bytes + 255) & ~255ULL; return r; };
  ushort* xb  = (ushort*)alloc((size_t)BT_ * C_ * 2);
  ushort* wqb = (ushort*)alloc((size_t)C_ * C_ * 2);
  ushort* wkb = (ushort*)alloc((size_t)C_ * C_ * 2);
  ushort* wvb = (ushort*)alloc((size_t)C_ * C_ * 2);
  ushort* wpb = (ushort*)alloc((size_t)C_ * C_ * 2);
  ushort* qb  = (ushort*)alloc((size_t)BT_ * C_ * 2);
  ushort* kb  = (ushort*)alloc((size_t)BT_ * C_ * 2);
  ushort* vtb = (ushort*)alloc((size_t)BT_ * C_ * 2);   // V^T [B,H,64,T]
  ushort* yb  = (ushort*)alloc((size_t)BT_ * C_ * 2);
  float* ctab = (float*)alloc((size_t)T_ * 32 * 4);
  float* stab = (float*)alloc((size_t)T_ * 32 * 4);

  k_f32_to_bf16<<<(BT_ * C_ / 4 + 255) / 256, 256, 0, stream>>>(x, xb, BT_ * C_ / 4);
  k_w_to_bf16<<<dim3((C_ * C_ / 4 + 255) / 256, 4), 256, 0, stream>>>(
      Wq, Wk, Wv, Wp, wqb, wkb, wvb, wpb, C_ * C_ / 4);
  k_rope_tab<<<T_ * 32 / 256, 256, 0, stream>>>(ctab, stab);

  // QKV projection with fused RoPE (q scaled by log2(e)/8 for exp2-domain softmax)
  k_qkv_gemm<<<dim3(BT_ / 128, 2304 / 128), 256, 0, stream>>>(
      xb, wqb, wkb, wvb, bq, bk, bv, ctab, stab, qb, kb, vtb);

  k_attn<<<dim3(768), 256, 0, stream>>>(qb, kb, vtb, yb);

  k_proj_gemm<<<dim3(BT_ / 128, C_ / 128), 256, 0, stream>>>(yb, wpb, bp, out);
}

// Round 13
// 208.398 us; speedup vs baseline: 1.2361x; 1.0506x over previous
//
#include <hip/hip_runtime.h>
#include <hip/hip_bf16.h>

#define B_  2
#define T_  4096
#define C_  768
#define H_  12
#define D_  64
#define BT_ (B_*T_)   // 8192

typedef __attribute__((ext_vector_type(8))) short short8;
typedef __attribute__((ext_vector_type(4))) short short4b;
typedef __attribute__((ext_vector_type(4))) float f32x4;

union U32x2 { unsigned u[2]; short4b s4; };

__device__ __forceinline__ ushort f2bf(float f) {
  union { __hip_bfloat16 b; ushort u; } cv; cv.b = __float2bfloat16(f); return cv.u;
}
__device__ __forceinline__ float bf2f(ushort u) {
  unsigned x = ((unsigned)u) << 16; float f; __builtin_memcpy(&f, &x, 4); return f;
}
// compiler-friendly pack (clang fuses to v_cvt_pk_bf16_f32)
__device__ __forceinline__ unsigned pack2(float a, float b) {
  return (unsigned)f2bf(a) | ((unsigned)f2bf(b) << 16);
}

// 16x16x16 bf16 MFMA (K=16, A/B k-granule = lg*4+i) — builtin-name guarded.
__device__ __forceinline__ f32x4 mfma16(short4b a, short4b b, f32x4 c) {
#if __has_builtin(__builtin_amdgcn_mfma_f32_16x16x16bf16_1k)
  return __builtin_amdgcn_mfma_f32_16x16x16bf16_1k(a, b, c, 0, 0, 0);
#elif __has_builtin(__builtin_amdgcn_mfma_f32_16x16x16_bf16)
  return __builtin_amdgcn_mfma_f32_16x16x16_bf16(a, b, c, 0, 0, 0);
#else
  asm("v_mfma_f32_16x16x16_bf16 %0, %1, %2, %0" : "+v"(c) : "v"(a), "v"(b));
  return c;
#endif
}

// ---------------- elementwise converts ----------------
__global__ void k_f32_to_bf16(const float* __restrict__ in, ushort* __restrict__ out, int n4) {
  int i = blockIdx.x * blockDim.x + threadIdx.x;
  if (i >= n4) return;
  const float4 v = ((const float4*)in)[i];
  ushort4 o;
  o.x = f2bf(v.x); o.y = f2bf(v.y); o.z = f2bf(v.z); o.w = f2bf(v.w);
  ((ushort4*)out)[i] = o;
}

// all four weight matrices in one launch (blockIdx.y selects)
__global__ void k_w_to_bf16(const float* __restrict__ w0, const float* __restrict__ w1,
                            const float* __restrict__ w2, const float* __restrict__ w3,
                            ushort* __restrict__ o0, ushort* __restrict__ o1,
                            ushort* __restrict__ o2, ushort* __restrict__ o3, int n4) {
  int i = blockIdx.x * blockDim.x + threadIdx.x;
  if (i >= n4) return;
  const int sel = blockIdx.y;
  const float* in = sel == 0 ? w0 : (sel == 1 ? w1 : (sel == 2 ? w2 : w3));
  ushort* out = sel == 0 ? o0 : (sel == 1 ? o1 : (sel == 2 ? o2 : o3));
  const float4 v = ((const float4*)in)[i];
  ushort4 o;
  o.x = f2bf(v.x); o.y = f2bf(v.y); o.z = f2bf(v.z); o.w = f2bf(v.w);
  ((ushort4*)out)[i] = o;
}

__global__ void k_rope_tab(float* __restrict__ ctab, float* __restrict__ stab) {
  int i = blockIdx.x * blockDim.x + threadIdx.x;  // T_*32 threads
  int t = i >> 5, p = i & 31;
  float inv = 1.0f / powf(10000.0f, (2.0f * (float)p) / 64.0f);
  float a = (float)t * inv;
  ctab[i] = cosf(a); stab[i] = sinf(a);
}

// ---------------- QKV projection GEMM (RoPE fused into q/k epilogue) ----------
// q,k -> [B,H,T,64] with RoPE applied (q also scaled by log2(e)/8);
// v -> TRANSPOSED [B,H,64,T] (attn consumes V^T fragments).
__global__ __launch_bounds__(256) void k_qkv_gemm(
    const ushort* __restrict__ xb, const ushort* __restrict__ wq,
    const ushort* __restrict__ wk, const ushort* __restrict__ wv,
    const float* __restrict__ bq, const float* __restrict__ bk, const float* __restrict__ bv,
    const float* __restrict__ ctab, const float* __restrict__ stab,
    ushort* __restrict__ qo, ushort* __restrict__ ko, ushort* __restrict__ vo) {
  __shared__ __align__(16) ushort As[128 * 72];
  __shared__ __align__(16) ushort Bs[128 * 72];
  const int tid = threadIdx.x, l = tid & 63, w = tid >> 6;
  const int lr = l & 15, lg = l >> 4;
  const int m0 = blockIdx.x * 128;
  const int n0g = blockIdx.y * 128;
  const int proj = n0g / 768;
  const int n0 = n0g % 768;
  const ushort* wsrc = proj == 0 ? wq : (proj == 1 ? wk : wv);
  const int wr = (w >> 1) * 64, wc = (w & 1) * 64;

  f32x4 acc[4][4];
  #pragma unroll
  for (int a = 0; a < 4; ++a)
    #pragma unroll
    for (int b = 0; b < 4; ++b) acc[a][b] = (f32x4){0.f, 0.f, 0.f, 0.f};

  for (int k0 = 0; k0 < 768; k0 += 64) {
    #pragma unroll
    for (int i = 0; i < 4; ++i) {
      int seg = tid + i * 256;
      int row = seg >> 3, c8 = (seg & 7) << 3;
      *(short8*)&As[row * 72 + c8] = *(const short8*)(xb + (size_t)(m0 + row) * 768 + k0 + c8);
      *(short8*)&Bs[row * 72 + c8] = *(const short8*)(wsrc + (size_t)(n0 + row) * 768 + k0 + c8);
    }
    __syncthreads();
    #pragma unroll
    for (int kk = 0; kk < 2; ++kk) {
      short8 af[4], bf[4];
      #pragma unroll
      for (int mi = 0; mi < 4; ++mi)
        af[mi] = *(const short8*)&As[(wr + mi * 16 + lr) * 72 + kk * 32 + lg * 8];
      #pragma unroll
      for (int ni = 0; ni < 4; ++ni)
        bf[ni] = *(const short8*)&Bs[(wc + ni * 16 + lr) * 72 + kk * 32 + lg * 8];
      #pragma unroll
      for (int mi = 0; mi < 4; ++mi)
        #pragma unroll
        for (int ni = 0; ni < 4; ++ni)
          acc[mi][ni] = __builtin_amdgcn_mfma_f32_16x16x32_bf16(af[mi], bf[ni], acc[mi][ni], 0, 0, 0);
    }
    __syncthreads();
  }

  const float* bias = proj == 0 ? bq : (proj == 1 ? bk : bv);
  if (proj == 2) {
    #pragma unroll
    for (int mi = 0; mi < 4; ++mi) {
      #pragma unroll
      for (int ni = 0; ni < 4; ++ni) {
        int colc = n0 + wc + ni * 16 + lr;
        float bb = bias[colc];
        int h = colc >> 6, d = colc & 63;
        int row0 = m0 + wr + mi * 16 + lg * 4;
        int b = row0 >> 12, t0 = row0 & (T_ - 1);
        ushort4 pk;
        pk.x = f2bf(acc[mi][ni][0] + bb);
        pk.y = f2bf(acc[mi][ni][1] + bb);
        pk.z = f2bf(acc[mi][ni][2] + bb);
        pk.w = f2bf(acc[mi][ni][3] + bb);
        *(ushort4*)(vo + (((size_t)b * H_ + h) * 64 + d) * T_ + t0) = pk;
      }
    }
  } else {
    // fused RoPE epilogue: d-pair partner lives in adjacent lane (lr^1).
    ushort* dst = proj == 0 ? qo : ko;
    const float qs = proj == 0 ? 0.18033688011112042f : 1.0f;   // log2(e)/8
    #pragma unroll
    for (int mi = 0; mi < 4; ++mi) {
      #pragma unroll
      for (int ni = 0; ni < 4; ++ni) {
        int colc = n0 + wc + ni * 16 + lr;
        float bb = bias[colc];
        int h = colc >> 6, d = colc & 63;
        const int pidx = d >> 1;
        const bool evn = (d & 1) == 0;
        #pragma unroll
        for (int j = 0; j < 4; ++j) {
          int row = m0 + wr + mi * 16 + lg * 4 + j;
          int b = row >> 12, t = row & (T_ - 1);
          float val = acc[mi][ni][j] + bb;          // biased (rope is post-bias)
          float prt = __shfl_xor(val, 1);           // partner d^1 (lane lr^1)
          float cc = ctab[(t << 5) + pidx];
          float ss = stab[(t << 5) + pidx];
          float ro = evn ? (val * cc - prt * ss) : (prt * ss + val * cc);
          dst[((((size_t)b * H_ + h) << 12) + t) * 64 + d] = f2bf(ro * qs);
        }
      }
    }
  }
}

// ---------------- output projection GEMM (f32 out) ----------------
__global__ __launch_bounds__(256) void k_proj_gemm(
    const ushort* __restrict__ yb, const ushort* __restrict__ wp,
    const float* __restrict__ bp, float* __restrict__ out) {
  __shared__ __align__(16) ushort As[128 * 72];
  __shared__ __align__(16) ushort Bs[128 * 72];
  const int tid = threadIdx.x, l = tid & 63, w = tid >> 6;
  const int lr = l & 15, lg = l >> 4;
  const int m0 = blockIdx.x * 128;
  const int n0 = blockIdx.y * 128;
  const int wr = (w >> 1) * 64, wc = (w & 1) * 64;

  f32x4 acc[4][4];
  #pragma unroll
  for (int a = 0; a < 4; ++a)
    #pragma unroll
    for (int b = 0; b < 4; ++b) acc[a][b] = (f32x4){0.f, 0.f, 0.f, 0.f};

  for (int k0 = 0; k0 < 768; k0 += 64) {
    #pragma unroll
    for (int i = 0; i < 4; ++i) {
      int seg = tid + i * 256;
      int row = seg >> 3, c8 = (seg & 7) << 3;
      *(short8*)&As[row * 72 + c8] = *(const short8*)(yb + (size_t)(m0 + row) * 768 + k0 + c8);
      *(short8*)&Bs[row * 72 + c8] = *(const short8*)(wp + (size_t)(n0 + row) * 768 + k0 + c8);
    }
    __syncthreads();
    #pragma unroll
    for (int kk = 0; kk < 2; ++kk) {
      short8 af[4], bf[4];
      #pragma unroll
      for (int mi = 0; mi < 4; ++mi)
        af[mi] = *(const short8*)&As[(wr + mi * 16 + lr) * 72 + kk * 32 + lg * 8];
      #pragma unroll
      for (int ni = 0; ni < 4; ++ni)
        bf[ni] = *(const short8*)&Bs[(wc + ni * 16 + lr) * 72 + kk * 32 + lg * 8];
      #pragma unroll
      for (int mi = 0; mi < 4; ++mi)
        #pragma unroll
        for (int ni = 0; ni < 4; ++ni)
          acc[mi][ni] = __builtin_amdgcn_mfma_f32_16x16x32_bf16(af[mi], bf[ni], acc[mi][ni], 0, 0, 0);
    }
    __syncthreads();
  }

  #pragma unroll
  for (int mi = 0; mi < 4; ++mi)
    #pragma unroll
    for (int ni = 0; ni < 4; ++ni) {
      int col = n0 + wc + ni * 16 + lr;
      float bb = bp[col];
      #pragma unroll
      for (int j = 0; j < 4; ++j) {
        int row = m0 + wr + mi * 16 + lg * 4 + j;
        out[(size_t)row * 768 + col] = acc[mi][ni][j] + bb;
      }
    }
}

// ---------------- causal flash attention: UNIFORM 65-iter blocks --------------
// grid 768 (R12-proven): block (p, bh) runs tile p then tile 63-p = 65 iters,
// all blocks identical duration, 3/CU all-resident. O^T = V^T P^T; PV via
// 16x16x16 (P in-lane); defer-max THR=8 with -mx folded into QK C-init.
// NEW vs R12 (VALU->MFMA shift):
//  - denominator ls accumulated by MFMA (ones-row trick): lsa = mfma16(ones,
//    pb[ks], lsa) -> deletes 16 adds + 2 cross-lane shuffles per iteration.
//  - defer-max test uses LANE-LOCAL max only (__any is group-global); the
//    2 group-max shuffles move inside the rare rescale branch.
__global__ __launch_bounds__(256) void k_attn(
    const ushort* __restrict__ q, const ushort* __restrict__ k,
    const ushort* __restrict__ vt, ushort* __restrict__ y) {
  __shared__ __align__(16) ushort Ks[2][64 * 64];
  __shared__ __align__(16) ushort Vs[2][64 * 64];
  const int tid = threadIdx.x, l = tid & 63, w = tid >> 6;
  const int lr = l & 15, lg = l >> 4;
  const int p = blockIdx.x & 31;
  const int bh = blockIdx.x >> 5;
  const size_t kpl = (size_t)bh * T_ * 64;
  const size_t vpl = (size_t)bh * 64 * T_;
  const int b = bh / H_, h = bh % H_;
  const short4b ones4 = { (short)0x3F80, (short)0x3F80, (short)0x3F80, (short)0x3F80 };

  #pragma unroll 1
  for (int ph = 0; ph < 2; ++ph) {
    const int t = ph == 0 ? p : 63 - p;
    const int nt = t + 1;
    const int qrow = t * 64 + w * 16 + lr;

    // Q fragments (B operand of S^T = K·Q: col=q=lane&15, k-rows = d)
    short8 qf[2];
    #pragma unroll
    for (int kk = 0; kk < 2; ++kk)
      qf[kk] = *(const short8*)(q + kpl + (size_t)qrow * 64 + kk * 32 + lg * 8);

    f32x4 o[4];
    f32x4 lsa = (f32x4){0.f, 0.f, 0.f, 0.f};   // MFMA-accumulated denominator
    float mx = 0.0f;   // mx=0 init: shift-invariant, keeps C-fold f32-exact
    #pragma unroll
    for (int c = 0; c < 4; ++c) o[c] = (f32x4){0.f, 0.f, 0.f, 0.f};

    __syncthreads();   // previous phase's LDS reads complete before re-staging
    // prologue: stage tile 0 into buf 0 (XOR-swizzled 16B slots)
    {
      #pragma unroll
      for (int i2 = 0; i2 < 2; ++i2) {
        const int r = w * 16 + i2 * 8 + (l >> 3);
        const int sl = (l & 7) ^ (r & 7);
        short8 s0 = *(const short8*)(k + kpl + (size_t)r * 64 + (l & 7) * 8);
        short8 v0 = *(const short8*)(vt + vpl + (size_t)r * T_ + (l & 7) * 8);
        *(short8*)&Ks[0][r * 64 + sl * 8] = s0;
        *(short8*)&Vs[0][r * 64 + sl * 8] = v0;
      }
    }

    int buf = 0;
    for (int kt = 0; kt < nt; ++kt) {
      __syncthreads();
      // async-split staging: issue next tile's global loads before compute
      short8 sk[2], sv[2];
      const bool pre = (kt + 1 < nt);
      if (pre) {
        #pragma unroll
        for (int i2 = 0; i2 < 2; ++i2) {
          const int r = w * 16 + i2 * 8 + (l >> 3);
          sk[i2] = *(const short8*)(k + kpl + (size_t)((kt + 1) * 64 + r) * 64 + (l & 7) * 8);
          sv[i2] = *(const short8*)(vt + vpl + (size_t)r * T_ + (kt + 1) * 64 + (l & 7) * 8);
        }
      }

      // ---- S^T = K·Q - mx (shift folded into MFMA C-init) ----
      const f32x4 zinit = (f32x4){-mx, -mx, -mx, -mx};
      f32x4 sT[4];
      #pragma unroll
      for (int c = 0; c < 4; ++c) {
        short8 kf0 = *(const short8*)&Ks[buf][(c * 16 + lr) * 64 + ((lg) ^ (lr & 7)) * 8];
        short8 kf1 = *(const short8*)&Ks[buf][(c * 16 + lr) * 64 + ((4 + lg) ^ (lr & 7)) * 8];
        f32x4 z = zinit;
        z = __builtin_amdgcn_mfma_f32_16x16x32_bf16(kf0, qf[0], z, 0, 0, 0);
        z = __builtin_amdgcn_mfma_f32_16x16x32_bf16(kf1, qf[1], z, 0, 0, 0);
        sT[c] = z;
      }

      // ---- softmax (lane-local state, q = lr); sT is RELATIVE to mx ----
      if (kt == t) {   // diagonal tile: causal mask (S^T row=key, col=q)
        #pragma unroll
        for (int c = 0; c < 4; ++c)
          #pragma unroll
          for (int jj = 0; jj < 4; ++jj)
            if (kt * 64 + c * 16 + lg * 4 + jj > qrow) sT[c][jj] = -1e30f;
      }
      float cm0 = fmaxf(fmaxf(fmaxf(sT[0][0], sT[0][1]), sT[0][2]), sT[0][3]);
      float cm1 = fmaxf(fmaxf(fmaxf(sT[1][0], sT[1][1]), sT[1][2]), sT[1][3]);
      float cm2 = fmaxf(fmaxf(fmaxf(sT[2][0], sT[2][1]), sT[2][2]), sT[2][3]);
      float cm3 = fmaxf(fmaxf(fmaxf(sT[3][0], sT[3][1]), sT[3][2]), sT[3][3]);
      const float lmax = fmaxf(fmaxf(cm0, cm1), fmaxf(cm2, cm3));   // lane-local
      // T13 defer-max: group test via __any on LOCAL max (no common-path shfl)
      if (__any(lmax > 8.0f)) {
        float g = fmaxf(lmax, __shfl_xor(lmax, 16));
        g = fmaxf(g, __shfl_xor(g, 32));
        g = fmaxf(g, 0.0f);
        const float corr = exp2f(-g);
        mx += g;
        lsa *= corr;
        #pragma unroll
        for (int c = 0; c < 4; ++c) o[c] *= corr;
        #pragma unroll
        for (int c = 0; c < 4; ++c)
          #pragma unroll
          for (int jj = 0; jj < 4; ++jj) sT[c][jj] -= g;
      }
      // common path: p = exp2(sT) directly — no subtraction, no reduction
      U32x2 pb[4];
      #pragma unroll
      for (int c = 0; c < 4; ++c) {
        float p0 = exp2f(sT[c][0]);
        float p1 = exp2f(sT[c][1]);
        float p2 = exp2f(sT[c][2]);
        float p3 = exp2f(sT[c][3]);
        pb[c].u[0] = pack2(p0, p1); pb[c].u[1] = pack2(p2, p3);
      }

      // ---- O^T += V^T·P^T and lsa += 1^T·P^T via 16x16x16 (P in-lane) ----
      __builtin_amdgcn_s_setprio(1);
      #pragma unroll
      for (int ks = 0; ks < 4; ++ks) {
        lsa = mfma16(ones4, pb[ks].s4, lsa);    // denominator on the MFMA pipe
        #pragma unroll
        for (int c = 0; c < 4; ++c) {
          const int row = c * 16 + lr;
          const int sl = (2 * ks + (lg >> 1)) ^ (row & 7);
          short4b va = *(const short4b*)&Vs[buf][row * 64 + sl * 8 + (lg & 1) * 4];
          o[c] = mfma16(va, pb[ks].s4, o[c]);
        }
      }
      __builtin_amdgcn_s_setprio(0);

      if (pre) {
        #pragma unroll
        for (int i2 = 0; i2 < 2; ++i2) {
          const int r = w * 16 + i2 * 8 + (l >> 3);
          const int sl = (l & 7) ^ (r & 7);
          *(short8*)&Ks[buf ^ 1][r * 64 + sl * 8] = sk[i2];
          *(short8*)&Vs[buf ^ 1][r * 64 + sl * 8] = sv[i2];
        }
      }
      buf ^= 1;
    }

    // phase epilogue: normalize (lane-local; lsa rows all equal) + write y
    const float linv = 1.0f / lsa[0];
    const size_t base = ((size_t)b * T_ + qrow) * C_ + h * 64;
    #pragma unroll
    for (int c = 0; c < 4; ++c) {
      ushort4 pk;
      pk.x = f2bf(o[c][0] * linv);
      pk.y = f2bf(o[c][1] * linv);
      pk.z = f2bf(o[c][2] * linv);
      pk.w = f2bf(o[c][3] * linv);
      *(ushort4*)(y + base + c * 16 + lg * 4) = pk;
    }
  }
}

extern "C" void kernel_launch(void* const* d_in, const int* in_sizes, int n_in,
                              void* d_out, int out_size, void* d_ws, size_t ws_size,
                              hipStream_t stream) {
  const float* x  = (const float*)d_in[0];
  const float* Wq = (const float*)d_in[1];
  const float* bq = (const float*)d_in[2];
  const float* Wk = (const float*)d_in[3];
  const float* bk = (const float*)d_in[4];
  const float* Wv = (const float*)d_in[5];
  const float* bv = (const float*)d_in[6];
  const float* Wp = (const float*)d_in[7];
  const float* bp = (const float*)d_in[8];
  float* out = (float*)d_out;

  // ws: exact R3-proven footprint (~69 MB)
  char* p = (char*)d_ws;
  auto alloc = [&](size_t bytes) { char* r = p; p += (bytes + 255) & ~255ULL; return r; };
  ushort* xb  = (ushort*)alloc((size_t)BT_ * C_ * 2);
  ushort* wqb = (ushort*)alloc((size_t)C_ * C_ * 2);
  ushort* wkb = (ushort*)alloc((size_t)C_ * C_ * 2);
  ushort* wvb = (ushort*)alloc((size_t)C_ * C_ * 2);
  ushort* wpb = (ushort*)alloc((size_t)C_ * C_ * 2);
  ushort* qb  = (ushort*)alloc((size_t)BT_ * C_ * 2);
  ushort* kb  = (ushort*)alloc((size_t)BT_ * C_ * 2);
  ushort* vtb = (ushort*)alloc((size_t)BT_ * C_ * 2);   // V^T [B,H,64,T]
  ushort* yb  = (ushort*)alloc((size_t)BT_ * C_ * 2);
  float* ctab = (float*)alloc((size_t)T_ * 32 * 4);
  float* stab = (float*)alloc((size_t)T_ * 32 * 4);

  k_f32_to_bf16<<<(BT_ * C_ / 4 + 255) / 256, 256, 0, stream>>>(x, xb, BT_ * C_ / 4);
  k_w_to_bf16<<<dim3((C_ * C_ / 4 + 255) / 256, 4), 256, 0, stream>>>(
      Wq, Wk, Wv, Wp, wqb, wkb, wvb, wpb, C_ * C_ / 4);
  k_rope_tab<<<T_ * 32 / 256, 256, 0, stream>>>(ctab, stab);

  // QKV projection with fused RoPE (q scaled by log2(e)/8 for exp2-domain softmax)
  k_qkv_gemm<<<dim3(BT_ / 128, 2304 / 128), 256, 0, stream>>>(
      xb, wqb, wkb, wvb, bq, bk, bv, ctab, stab, qb, kb, vtb);

  k_attn<<<dim3(768), 256, 0, stream>>>(qb, kb, vtb, yb);

  k_proj_gemm<<<dim3(BT_ / 128, C_ / 128), 256, 0, stream>>>(yb, wpb, bp, out);
}